// Round 2
// baseline (1062.550 us; speedup 1.0000x reference)
//
#include <hip/hip_runtime.h>

// GCN via CSR-by-destination build + gather (no feature atomics).
// N=100000, E=3200000, G=512, F: 64 -> 16 -> 16 -> 2.

// Per edge: weighted degree + in-degree count histogram.
__global__ void deg_cnt_kernel(const int* __restrict__ col, const float* __restrict__ ew,
                               float* __restrict__ deg, unsigned* __restrict__ cnt, int E) {
    int t = blockIdx.x * blockDim.x + threadIdx.x;
    if (t >= E) return;
    int c = col[t];
    atomicAdd(&deg[c], ew[t]);
    atomicAdd(&cnt[c], 1u);
}

// deg -> dinv in place; also count nodes per graph.
__global__ void dinv_kernel(float* __restrict__ deg, const int* __restrict__ batch,
                            float* __restrict__ cntg, int N) {
    int i = blockIdx.x * blockDim.x + threadIdx.x;
    if (i >= N) return;
    deg[i] = rsqrtf(deg[i] + 1.0f);   // self-loop adds +1
    atomicAdd(&cntg[batch[i]], 1.0f);
}

// Single-block exclusive scan of cnt[N] -> offs[N+1], cursor[N].
__global__ void scan_kernel(const unsigned* __restrict__ cnt, unsigned* __restrict__ offs,
                            unsigned* __restrict__ cursor, int N) {
    __shared__ unsigned partial[1024];
    int tid = threadIdx.x;
    int chunk = (N + 1023) / 1024;
    int lo = tid * chunk;
    int hi = lo + chunk; if (hi > N) hi = N; if (lo > N) lo = N;
    unsigned s = 0;
    for (int i = lo; i < hi; ++i) s += cnt[i];
    partial[tid] = s;
    __syncthreads();
    for (int d = 1; d < 1024; d <<= 1) {
        unsigned v = (tid >= d) ? partial[tid - d] : 0u;
        __syncthreads();
        partial[tid] += v;
        __syncthreads();
    }
    unsigned run = (tid == 0) ? 0u : partial[tid - 1];
    for (int i = lo; i < hi; ++i) {
        offs[i] = run; cursor[i] = run;
        run += cnt[i];
    }
    if (tid == 1023) offs[N] = run;
}

// Scatter edges into CSR-by-col order, norm precomputed (shared by both layers).
__global__ void scatter_kernel(const int* __restrict__ row, const int* __restrict__ col,
                               const float* __restrict__ ew, const float* __restrict__ dinv,
                               unsigned* __restrict__ cursor, int2* __restrict__ epack, int E) {
    int t = blockIdx.x * blockDim.x + threadIdx.x;
    if (t >= E) return;
    int r = row[t], c = col[t];
    float norm = dinv[r] * ew[t] * dinv[c];
    unsigned p = atomicAdd(&cursor[c], 1u);
    epack[p] = make_int2(r, __float_as_int(norm));
}

// xw = x @ W1   (N x 64) @ (64 x 16), one thread per node row
__global__ void gemm1_kernel(const float* __restrict__ x, const float* __restrict__ W1,
                             float* __restrict__ xw, int N) {
    __shared__ float Ws[64 * 16];
    for (int k = threadIdx.x; k < 64 * 16; k += blockDim.x) Ws[k] = W1[k];
    __syncthreads();
    int i = blockIdx.x * blockDim.x + threadIdx.x;
    if (i >= N) return;
    const float4* xp = reinterpret_cast<const float4*>(x + (size_t)i * 64);
    float acc[16];
#pragma unroll
    for (int j = 0; j < 16; ++j) acc[j] = 0.0f;
#pragma unroll
    for (int k4 = 0; k4 < 16; ++k4) {
        float4 xv = xp[k4];
#pragma unroll
        for (int j = 0; j < 16; ++j) {
            acc[j] += xv.x * Ws[(k4 * 4 + 0) * 16 + j]
                    + xv.y * Ws[(k4 * 4 + 1) * 16 + j]
                    + xv.z * Ws[(k4 * 4 + 2) * 16 + j]
                    + xv.w * Ws[(k4 * 4 + 3) * 16 + j];
        }
    }
    float4* op = reinterpret_cast<float4*>(xw + (size_t)i * 16);
    op[0] = make_float4(acc[0],  acc[1],  acc[2],  acc[3]);
    op[1] = make_float4(acc[4],  acc[5],  acc[6],  acc[7]);
    op[2] = make_float4(acc[8],  acc[9],  acc[10], acc[11]);
    op[3] = make_float4(acc[12], acc[13], acc[14], acc[15]);
}

// Gather conv: out[c][j] = dinv[c]^2*xw[c][j] + sum_{e in CSR[c]} norm_e * xw[src_e][j]
// 16 lanes per node (lane j owns feature j).
__global__ void gather_kernel(const unsigned* __restrict__ offs, const int2* __restrict__ epack,
                              const float* __restrict__ dinv, const float* __restrict__ xw,
                              float* __restrict__ out, int N) {
    int t = blockIdx.x * blockDim.x + threadIdx.x;
    int node = t >> 4, j = t & 15;
    if (node >= N) return;
    float d = dinv[node];
    float acc = d * d * xw[node * 16 + j];
    unsigned s = offs[node], e = offs[node + 1];
    for (unsigned k = s; k < e; ++k) {
        int2 p = epack[k];
        acc += __int_as_float(p.y) * xw[p.x * 16 + j];
    }
    out[node * 16 + j] = acc;
}

// Same gather, but fused bias+ReLU+mean-pool contribution (layer-2 epilogue).
__global__ void gather_pool_kernel(const unsigned* __restrict__ offs, const int2* __restrict__ epack,
                                   const float* __restrict__ dinv, const float* __restrict__ xw,
                                   const float* __restrict__ b2, const int* __restrict__ batch,
                                   float* __restrict__ pooled, int N) {
    int t = blockIdx.x * blockDim.x + threadIdx.x;
    int node = t >> 4, j = t & 15;
    if (node >= N) return;
    float d = dinv[node];
    float acc = d * d * xw[node * 16 + j];
    unsigned s = offs[node], e = offs[node + 1];
    for (unsigned k = s; k < e; ++k) {
        int2 p = epack[k];
        acc += __int_as_float(p.y) * xw[p.x * 16 + j];
    }
    float v = fmaxf(acc + b2[j], 0.0f);
    atomicAdd(&pooled[batch[node] * 16 + j], v);
}

// xw2 = relu(in + b1) @ W2   (N x 16) @ (16 x 16)
__global__ void gemm2_kernel(const float* __restrict__ in, const float* __restrict__ b,
                             const float* __restrict__ W, float* __restrict__ xw, int N) {
    __shared__ float Ws[16 * 16];
    __shared__ float bs[16];
    if (threadIdx.x < 16 * 16) Ws[threadIdx.x] = W[threadIdx.x];
    if (threadIdx.x < 16) bs[threadIdx.x] = b[threadIdx.x];
    __syncthreads();
    int i = blockIdx.x * blockDim.x + threadIdx.x;
    if (i >= N) return;
    const float4* ip = reinterpret_cast<const float4*>(in + (size_t)i * 16);
    float h[16];
#pragma unroll
    for (int q = 0; q < 4; ++q) {
        float4 v = ip[q];
        h[q * 4 + 0] = fmaxf(v.x + bs[q * 4 + 0], 0.0f);
        h[q * 4 + 1] = fmaxf(v.y + bs[q * 4 + 1], 0.0f);
        h[q * 4 + 2] = fmaxf(v.z + bs[q * 4 + 2], 0.0f);
        h[q * 4 + 3] = fmaxf(v.w + bs[q * 4 + 3], 0.0f);
    }
    float acc[16];
#pragma unroll
    for (int j = 0; j < 16; ++j) acc[j] = 0.0f;
#pragma unroll
    for (int k = 0; k < 16; ++k) {
#pragma unroll
        for (int j = 0; j < 16; ++j) acc[j] += h[k] * Ws[k * 16 + j];
    }
    float4* op = reinterpret_cast<float4*>(xw + (size_t)i * 16);
    op[0] = make_float4(acc[0],  acc[1],  acc[2],  acc[3]);
    op[1] = make_float4(acc[4],  acc[5],  acc[6],  acc[7]);
    op[2] = make_float4(acc[8],  acc[9],  acc[10], acc[11]);
    op[3] = make_float4(acc[12], acc[13], acc[14], acc[15]);
}

// logits = (pooled/cnt) @ Wfc + bfc ; out = log_softmax over 2 classes
__global__ void head_kernel(const float* __restrict__ pooled, const float* __restrict__ cnt,
                            const float* __restrict__ Wfc, const float* __restrict__ bfc,
                            float* __restrict__ out, int G) {
    int g = blockIdx.x * blockDim.x + threadIdx.x;
    if (g >= G) return;
    float c = fmaxf(cnt[g], 1.0f);
    float l0 = bfc[0], l1 = bfc[1];
#pragma unroll
    for (int j = 0; j < 16; ++j) {
        float p = pooled[g * 16 + j] / c;
        l0 += p * Wfc[j * 2 + 0];
        l1 += p * Wfc[j * 2 + 1];
    }
    float m = fmaxf(l0, l1);
    float lse = m + logf(expf(l0 - m) + expf(l1 - m));
    out[g * 2 + 0] = l0 - lse;
    out[g * 2 + 1] = l1 - lse;
}

extern "C" void kernel_launch(void* const* d_in, const int* in_sizes, int n_in,
                              void* d_out, int out_size, void* d_ws, size_t ws_size,
                              hipStream_t stream) {
    const float* x   = (const float*)d_in[0];
    const int*   ei  = (const int*)d_in[1];
    const float* ew  = (const float*)d_in[2];
    const int*   bat = (const int*)d_in[3];
    const float* W1  = (const float*)d_in[4];
    const float* b1  = (const float*)d_in[5];
    const float* W2  = (const float*)d_in[6];
    const float* b2  = (const float*)d_in[7];
    const float* Wfc = (const float*)d_in[8];
    const float* bfc = (const float*)d_in[9];
    float* out = (float*)d_out;

    const int N = in_sizes[0] / 64;   // 100000
    const int E = in_sizes[2];        // 3200000
    const int G = out_size / 2;       // 512

    const int* row = ei;
    const int* col = ei + E;

    // workspace layout (4-byte units; epack first for 8B/16B alignment)
    char* wsb = (char*)d_ws;
    int2*     epack  = (int2*)wsb;                                   // E int2
    float*    xw1    = (float*)(wsb + (size_t)E * 8);                // N*16
    float*    out1   = xw1 + (size_t)N * 16;                         // N*16
    float*    dinv   = out1 + (size_t)N * 16;                        // N (deg -> dinv)
    unsigned* cnt    = (unsigned*)(dinv + N);                        // N
    unsigned* offs   = cnt + N;                                      // N+1
    unsigned* cursor = offs + N + 1;                                 // N
    float*    pooled = (float*)(cursor + N);                         // G*16
    float*    cntg   = pooled + (size_t)G * 16;                      // G
    float*    xw2    = xw1;   // reuse after gemm2 consumed out1? no: gemm2 reads out1, writes xw2(=xw1) - xw1 dead by then

    hipMemsetAsync(dinv, 0, (size_t)N * 2 * sizeof(float), stream);            // dinv + cnt
    hipMemsetAsync(pooled, 0, (size_t)(G * 16 + G) * sizeof(float), stream);   // pooled + cntg

    const int B = 256;
    const int nbN   = (N + B - 1) / B;
    const int nbN16 = (N * 16 + B - 1) / B;
    const int nbE   = (E + B - 1) / B;

    deg_cnt_kernel<<<nbE, B, 0, stream>>>(col, ew, dinv, cnt, E);
    dinv_kernel<<<nbN, B, 0, stream>>>(dinv, bat, cntg, N);
    scan_kernel<<<1, 1024, 0, stream>>>(cnt, offs, cursor, N);
    scatter_kernel<<<nbE, B, 0, stream>>>(row, col, ew, dinv, cursor, epack, E);

    gemm1_kernel<<<nbN, B, 0, stream>>>(x, W1, xw1, N);
    gather_kernel<<<nbN16, B, 0, stream>>>(offs, epack, dinv, xw1, out1, N);

    gemm2_kernel<<<nbN, B, 0, stream>>>(out1, b1, W2, xw2, N);
    gather_pool_kernel<<<nbN16, B, 0, stream>>>(offs, epack, dinv, xw2, b2, bat, pooled, N);

    head_kernel<<<(G + B - 1) / B, B, 0, stream>>>(pooled, cntg, Wfc, bfc, out, G);
}

// Round 3
// 606.348 us; speedup vs baseline: 1.7524x; 1.7524x over previous
//
#include <hip/hip_runtime.h>

// GCN with per-XCD privatized accumulators + XCD-L2-scope atomics.
// Device-scope atomics on MI355X route past the non-coherent per-XCD L2s to the
// memory-side coherent point (~32B EA granule per scalar atomic — measured R1/R2).
// Plain global_atomic_add_f32 (no sc bits) executes at the local XCD L2; we make
// that correct by giving each XCD its own replica (indexed by HW_REG_XCC_ID) and
// reducing the 8 replicas in a follow-up kernel (kernel-end flush gives visibility).
// N=100000, E=3200000, G=512, F: 64 -> 16 -> 16 -> 2.

#define NXCD 8

__device__ __forceinline__ int get_xcc() {
    int x;
    asm volatile("s_getreg_b32 %0, hwreg(HW_REG_XCC_ID)" : "=s"(x));
    return x & (NXCD - 1);
}

// L2-local (XCD-scope) float atomic add: no sc0/sc1 -> executes at this XCD's L2.
__device__ __forceinline__ void atomAddF32L2(float* p, float v) {
    asm volatile("global_atomic_add_f32 %0, %1, off" :: "v"(p), "v"(v) : "memory");
}

// ---- degree ----
template <int R>
__global__ void deg_kernel(const int* __restrict__ col, const float* __restrict__ ew,
                           float* __restrict__ deg_priv, int N, int E) {
    int t = blockIdx.x * blockDim.x + threadIdx.x;
    if (t >= E) return;
    int c = col[t];
    if (R == NXCD) atomAddF32L2(&deg_priv[get_xcc() * N + c], ew[t]);
    else           atomicAdd(&deg_priv[c], ew[t]);
}

// dinv[i] = rsqrt(1 + sum_replicas deg); also per-graph node counts.
template <int R>
__global__ void dinv_kernel(const float* __restrict__ deg_priv, float* __restrict__ dinv,
                            const int* __restrict__ batch, float* __restrict__ cntg_priv,
                            int N, int G) {
    int i = blockIdx.x * blockDim.x + threadIdx.x;
    if (i >= N) return;
    float s = 0.0f;
#pragma unroll
    for (int x = 0; x < R; ++x) s += deg_priv[x * N + i];
    dinv[i] = rsqrtf(s + 1.0f);
    int g = batch[i];
    if (R == NXCD) atomAddF32L2(&cntg_priv[get_xcc() * G + g], 1.0f);
    else           atomicAdd(&cntg_priv[g], 1.0f);
}

// ---- dense GEMMs ----
__global__ void gemm1_kernel(const float* __restrict__ x, const float* __restrict__ W1,
                             float* __restrict__ xw, int N) {
    __shared__ float Ws[64 * 16];
    for (int k = threadIdx.x; k < 64 * 16; k += blockDim.x) Ws[k] = W1[k];
    __syncthreads();
    int i = blockIdx.x * blockDim.x + threadIdx.x;
    if (i >= N) return;
    const float4* xp = reinterpret_cast<const float4*>(x + (size_t)i * 64);
    float acc[16];
#pragma unroll
    for (int j = 0; j < 16; ++j) acc[j] = 0.0f;
#pragma unroll
    for (int k4 = 0; k4 < 16; ++k4) {
        float4 xv = xp[k4];
#pragma unroll
        for (int j = 0; j < 16; ++j) {
            acc[j] += xv.x * Ws[(k4 * 4 + 0) * 16 + j]
                    + xv.y * Ws[(k4 * 4 + 1) * 16 + j]
                    + xv.z * Ws[(k4 * 4 + 2) * 16 + j]
                    + xv.w * Ws[(k4 * 4 + 3) * 16 + j];
        }
    }
    float4* op = reinterpret_cast<float4*>(xw + (size_t)i * 16);
    op[0] = make_float4(acc[0],  acc[1],  acc[2],  acc[3]);
    op[1] = make_float4(acc[4],  acc[5],  acc[6],  acc[7]);
    op[2] = make_float4(acc[8],  acc[9],  acc[10], acc[11]);
    op[3] = make_float4(acc[12], acc[13], acc[14], acc[15]);
}

// xw2 = relu(in + b) @ W2   (N x 16) @ (16 x 16)
__global__ void gemm2_kernel(const float* __restrict__ in, const float* __restrict__ b,
                             const float* __restrict__ W, float* __restrict__ xw, int N) {
    __shared__ float Ws[16 * 16];
    __shared__ float bs[16];
    if (threadIdx.x < 16 * 16) Ws[threadIdx.x] = W[threadIdx.x];
    if (threadIdx.x < 16) bs[threadIdx.x] = b[threadIdx.x];
    __syncthreads();
    int i = blockIdx.x * blockDim.x + threadIdx.x;
    if (i >= N) return;
    const float4* ip = reinterpret_cast<const float4*>(in + (size_t)i * 16);
    float h[16];
#pragma unroll
    for (int q = 0; q < 4; ++q) {
        float4 v = ip[q];
        h[q * 4 + 0] = fmaxf(v.x + bs[q * 4 + 0], 0.0f);
        h[q * 4 + 1] = fmaxf(v.y + bs[q * 4 + 1], 0.0f);
        h[q * 4 + 2] = fmaxf(v.z + bs[q * 4 + 2], 0.0f);
        h[q * 4 + 3] = fmaxf(v.w + bs[q * 4 + 3], 0.0f);
    }
    float acc[16];
#pragma unroll
    for (int j = 0; j < 16; ++j) acc[j] = 0.0f;
#pragma unroll
    for (int k = 0; k < 16; ++k) {
#pragma unroll
        for (int j = 0; j < 16; ++j) acc[j] += h[k] * Ws[k * 16 + j];
    }
    float4* op = reinterpret_cast<float4*>(xw + (size_t)i * 16);
    op[0] = make_float4(acc[0],  acc[1],  acc[2],  acc[3]);
    op[1] = make_float4(acc[4],  acc[5],  acc[6],  acc[7]);
    op[2] = make_float4(acc[8],  acc[9],  acc[10], acc[11]);
    op[3] = make_float4(acc[12], acc[13], acc[14], acc[15]);
}

// ---- message scatter: 16 lanes per edge, lane j owns feature j ----
template <int R>
__global__ void edge_kernel(const int* __restrict__ row, const int* __restrict__ col,
                            const float* __restrict__ ew, const float* __restrict__ dinv,
                            const float* __restrict__ xw, float* __restrict__ out_priv,
                            int N, int E) {
    int t = blockIdx.x * blockDim.x + threadIdx.x;
    if (t >= E * 16) return;
    int e = t >> 4, j = t & 15;
    int r = row[e], c = col[e];
    float norm = dinv[r] * ew[e] * dinv[c];
    float v = norm * xw[r * 16 + j];
    if (R == NXCD) atomAddF32L2(&out_priv[((size_t)get_xcc() * N + c) * 16 + j], v);
    else           atomicAdd(&out_priv[c * 16 + j], v);
}

// ---- reduce replicas + self-loop; optional re-zero; optional fused bias/relu/pool ----
template <int R, bool ZERO, bool POOL>
__global__ void reduce_kernel(float* __restrict__ out_priv, const float* __restrict__ dinv,
                              const float* __restrict__ xw, float* __restrict__ out,
                              const float* __restrict__ b2, const int* __restrict__ batch,
                              float* __restrict__ pool_priv, int N, int G) {
    int t = blockIdx.x * blockDim.x + threadIdx.x;
    if (t >= N * 16) return;
    int i = t >> 4, j = t & 15;
    float d = dinv[i];
    float acc = d * d * xw[t];
    size_t n16 = (size_t)N * 16;
#pragma unroll
    for (int x = 0; x < R; ++x) {
        acc += out_priv[x * n16 + t];
        if (ZERO) out_priv[x * n16 + t] = 0.0f;
    }
    if (!POOL) {
        out[t] = acc;
    } else {
        float v = fmaxf(acc + b2[j], 0.0f);
        int g = batch[i];
        if (R == NXCD) atomAddF32L2(&pool_priv[((size_t)get_xcc() * G + g) * 16 + j], v);
        else           atomicAdd(&pool_priv[g * 16 + j], v);
    }
}

// ---- head: reduce pool replicas, mean, FC, log_softmax ----
template <int R>
__global__ void head_kernel(const float* __restrict__ pool_priv, const float* __restrict__ cntg_priv,
                            const float* __restrict__ Wfc, const float* __restrict__ bfc,
                            float* __restrict__ out, int G) {
    int g = blockIdx.x * blockDim.x + threadIdx.x;
    if (g >= G) return;
    float c = 0.0f;
#pragma unroll
    for (int x = 0; x < R; ++x) c += cntg_priv[x * G + g];
    c = fmaxf(c, 1.0f);
    float l0 = bfc[0], l1 = bfc[1];
#pragma unroll
    for (int j = 0; j < 16; ++j) {
        float p = 0.0f;
#pragma unroll
        for (int x = 0; x < R; ++x) p += pool_priv[((size_t)x * G + g) * 16 + j];
        p /= c;
        l0 += p * Wfc[j * 2 + 0];
        l1 += p * Wfc[j * 2 + 1];
    }
    float m = fmaxf(l0, l1);
    float lse = m + logf(expf(l0 - m) + expf(l1 - m));
    out[g * 2 + 0] = l0 - lse;
    out[g * 2 + 1] = l1 - lse;
}

extern "C" void kernel_launch(void* const* d_in, const int* in_sizes, int n_in,
                              void* d_out, int out_size, void* d_ws, size_t ws_size,
                              hipStream_t stream) {
    const float* x   = (const float*)d_in[0];
    const int*   ei  = (const int*)d_in[1];
    const float* ew  = (const float*)d_in[2];
    const int*   bat = (const int*)d_in[3];
    const float* W1  = (const float*)d_in[4];
    const float* b1  = (const float*)d_in[5];
    const float* W2  = (const float*)d_in[6];
    const float* b2  = (const float*)d_in[7];
    const float* Wfc = (const float*)d_in[8];
    const float* bfc = (const float*)d_in[9];
    float* out = (float*)d_out;

    const int N = in_sizes[0] / 64;   // 100000
    const int E = in_sizes[2];        // 3200000
    const int G = out_size / 2;       // 512

    const int* row = ei;
    const int* col = ei + E;

    const size_t n16 = (size_t)N * 16;

    // Decide privatized (R=8, L2-scope atomics) vs fallback (R=1, device atomics)
    // Layout: [out_priv R*n16][deg_priv R*N][pool_priv R*G*16][cntg_priv R*G]
    //         [xw1 n16][out1 n16][dinv N]
    auto plan_bytes = [&](int R) -> size_t {
        return ((size_t)R * n16 + (size_t)R * N + (size_t)R * G * 16 + (size_t)R * G
                + n16 + n16 + N) * sizeof(float);
    };
    const int R = (ws_size >= plan_bytes(NXCD)) ? NXCD : 1;

    float* ws       = (float*)d_ws;
    float* out_priv = ws;
    float* deg_priv = out_priv + (size_t)R * n16;
    float* pool_priv= deg_priv + (size_t)R * N;
    float* cntg_priv= pool_priv + (size_t)R * G * 16;
    float* xw1      = cntg_priv + (size_t)R * G;
    float* out1     = xw1 + n16;
    float* dinv     = out1 + n16;
    float* xw2      = xw1;  // gemm2 reads out1, xw1 is dead by then

    // zero all accumulators in one contiguous memset
    size_t zbytes = ((size_t)R * n16 + (size_t)R * N + (size_t)R * G * 16 + (size_t)R * G) * sizeof(float);
    hipMemsetAsync(out_priv, 0, zbytes, stream);

    const int B = 256;
    const int nbN   = (N + B - 1) / B;
    const int nbN16 = (int)((n16 + B - 1) / B);
    const int nbE   = (E + B - 1) / B;
    const int nbE16 = (int)(((long long)E * 16 + B - 1) / B);

    if (R == NXCD) {
        deg_kernel<NXCD><<<nbE, B, 0, stream>>>(col, ew, deg_priv, N, E);
        dinv_kernel<NXCD><<<nbN, B, 0, stream>>>(deg_priv, dinv, bat, cntg_priv, N, G);
        gemm1_kernel<<<nbN, B, 0, stream>>>(x, W1, xw1, N);
        edge_kernel<NXCD><<<nbE16, B, 0, stream>>>(row, col, ew, dinv, xw1, out_priv, N, E);
        reduce_kernel<NXCD, true, false><<<nbN16, B, 0, stream>>>(out_priv, dinv, xw1, out1,
                                                                  nullptr, nullptr, nullptr, N, G);
        gemm2_kernel<<<nbN, B, 0, stream>>>(out1, b1, W2, xw2, N);
        edge_kernel<NXCD><<<nbE16, B, 0, stream>>>(row, col, ew, dinv, xw2, out_priv, N, E);
        reduce_kernel<NXCD, false, true><<<nbN16, B, 0, stream>>>(out_priv, dinv, xw2, nullptr,
                                                                  b2, bat, pool_priv, N, G);
        head_kernel<NXCD><<<(G + B - 1) / B, B, 0, stream>>>(pool_priv, cntg_priv, Wfc, bfc, out, G);
    } else {
        deg_kernel<1><<<nbE, B, 0, stream>>>(col, ew, deg_priv, N, E);
        dinv_kernel<1><<<nbN, B, 0, stream>>>(deg_priv, dinv, bat, cntg_priv, N, G);
        gemm1_kernel<<<nbN, B, 0, stream>>>(x, W1, xw1, N);
        edge_kernel<1><<<nbE16, B, 0, stream>>>(row, col, ew, dinv, xw1, out_priv, N, E);
        reduce_kernel<1, true, false><<<nbN16, B, 0, stream>>>(out_priv, dinv, xw1, out1,
                                                               nullptr, nullptr, nullptr, N, G);
        gemm2_kernel<<<nbN, B, 0, stream>>>(out1, b1, W2, xw2, N);
        edge_kernel<1><<<nbE16, B, 0, stream>>>(row, col, ew, dinv, xw2, out_priv, N, E);
        reduce_kernel<1, false, true><<<nbN16, B, 0, stream>>>(out_priv, dinv, xw2, nullptr,
                                                               b2, bat, pool_priv, N, G);
        head_kernel<1><<<(G + B - 1) / B, B, 0, stream>>>(pool_priv, cntg_priv, Wfc, bfc, out, G);
    }
}